// Round 1
// baseline (1759.171 us; speedup 1.0000x reference)
//
#include <hip/hip_runtime.h>
#include <hip/hip_bf16.h>
#include <math.h>

// ---------------- problem constants (derived at launch from in_sizes) -------
// N=50000, E=800000, D_IN=256, D_E=64, H1=H2=128, N_OUT=64

#define GBN 64
#define GBO 64
#define GBK 16

// ---------------------------------------------------------------------------
// CSR build: degree count -> exclusive scan -> fill
// ---------------------------------------------------------------------------
__global__ void count_deg(const int* __restrict__ dst, int* __restrict__ cnt, int E) {
    int e = blockIdx.x * blockDim.x + threadIdx.x;
    if (e < E) atomicAdd(&cnt[dst[e]], 1);
}

__global__ __launch_bounds__(1024) void scan_a(const int* __restrict__ cnt,
                                               int* __restrict__ out,
                                               int* __restrict__ partials, int N) {
    __shared__ int sh[1024];
    int tid = threadIdx.x;
    int gid = blockIdx.x * 1024 + tid;
    int v = (gid < N) ? cnt[gid] : 0;   // element N (and beyond) contributes 0
    sh[tid] = v;
    for (int off = 1; off < 1024; off <<= 1) {
        __syncthreads();
        int add = (tid >= off) ? sh[tid - off] : 0;
        __syncthreads();
        sh[tid] += add;
    }
    __syncthreads();
    if (gid <= N) out[gid] = sh[tid] - v;            // exclusive within block
    if (tid == 1023) partials[blockIdx.x] = sh[1023]; // block total
}

__global__ void scan_b(int* __restrict__ partials, int nb) {
    if (threadIdx.x == 0 && blockIdx.x == 0) {
        int run = 0;
        for (int i = 0; i < nb; ++i) { int t = partials[i]; partials[i] = run; run += t; }
    }
}

__global__ __launch_bounds__(1024) void scan_c(int* __restrict__ out,
                                               const int* __restrict__ partials,
                                               int* __restrict__ fillb, int N) {
    int gid = blockIdx.x * 1024 + threadIdx.x;
    if (gid <= N) {
        int v = out[gid] + partials[blockIdx.x];
        out[gid] = v;
        fillb[gid] = v;
    }
}

__global__ void fill_edges(const int* __restrict__ src, const int* __restrict__ dst,
                           int* __restrict__ fillb, int* __restrict__ esrc,
                           int* __restrict__ eidb, int E) {
    int e = blockIdx.x * blockDim.x + threadIdx.x;
    if (e < E) {
        int d = dst[e];
        int slot = atomicAdd(&fillb[d], 1);
        esrc[slot] = src[e];
        eidb[slot] = e;
    }
}

// ---------------------------------------------------------------------------
// tiny transpose: We (128x64) -> WeT (64x128)
// ---------------------------------------------------------------------------
__global__ void transpose_we(const float* __restrict__ We, float* __restrict__ WeT) {
    int i = blockIdx.x * blockDim.x + threadIdx.x;
    if (i < 128 * 64) {
        int r = i >> 6, c = i & 63;
        WeT[c * 128 + r] = We[i];
    }
}

// ---------------------------------------------------------------------------
// Generic NT GEMM: Out[n][o] = bias[o] + sum_k X[n][k] * W[o][k]
// X: Nrows x K (leading dim ldx), W: O x K row-major, Out: Nrows x O (ld ldo)
// tile 64x64, K-chunk 16, 256 threads, 4x4 per thread
// ---------------------------------------------------------------------------
__global__ __launch_bounds__(256) void gemm_nt(const float* __restrict__ X, int ldx,
                                               const float* __restrict__ W,
                                               const float* __restrict__ bias,
                                               float* __restrict__ Out, int ldo,
                                               int Nrows, int K) {
    __shared__ float Xs[GBK][GBN];
    __shared__ float Ws[GBK][GBO];
    int n0 = blockIdx.x * GBN;
    int o0 = blockIdx.y * GBO;
    int t  = threadIdx.x;
    int tx = t & 15, ty = t >> 4;
    int lr = t >> 2;          // 0..63 row within tile
    int lk = (t & 3) * 4;     // k offset 0,4,8,12
    float acc[4][4] = {};
    for (int k0 = 0; k0 < K; k0 += GBK) {
        {
            int gr = n0 + lr;
            float4 xv = make_float4(0.f, 0.f, 0.f, 0.f);
            if (gr < Nrows)
                xv = *reinterpret_cast<const float4*>(&X[(size_t)gr * ldx + k0 + lk]);
            Xs[lk + 0][lr] = xv.x; Xs[lk + 1][lr] = xv.y;
            Xs[lk + 2][lr] = xv.z; Xs[lk + 3][lr] = xv.w;
            int go = o0 + lr;
            float4 wv = *reinterpret_cast<const float4*>(&W[(size_t)go * K + k0 + lk]);
            Ws[lk + 0][lr] = wv.x; Ws[lk + 1][lr] = wv.y;
            Ws[lk + 2][lr] = wv.z; Ws[lk + 3][lr] = wv.w;
        }
        __syncthreads();
#pragma unroll
        for (int k = 0; k < GBK; ++k) {
            float4 av = *reinterpret_cast<const float4*>(&Xs[k][ty * 4]);
            float4 bv = *reinterpret_cast<const float4*>(&Ws[k][tx * 4]);
            float a_[4] = {av.x, av.y, av.z, av.w};
            float b_[4] = {bv.x, bv.y, bv.z, bv.w};
#pragma unroll
            for (int i = 0; i < 4; ++i)
#pragma unroll
                for (int j = 0; j < 4; ++j)
                    acc[i][j] = fmaf(a_[i], b_[j], acc[i][j]);
        }
        __syncthreads();
    }
#pragma unroll
    for (int i = 0; i < 4; ++i) {
        int r = n0 + ty * 4 + i;
        if (r < Nrows) {
            int oc = o0 + tx * 4;
            float4 o4;
            o4.x = acc[i][0]; o4.y = acc[i][1]; o4.z = acc[i][2]; o4.w = acc[i][3];
            if (bias) {
                o4.x += bias[oc + 0]; o4.y += bias[oc + 1];
                o4.z += bias[oc + 2]; o4.w += bias[oc + 3];
            }
            *reinterpret_cast<float4*>(&Out[(size_t)r * ldo + oc]) = o4;
        }
    }
}

// ---------------------------------------------------------------------------
// Fused attention + epilogue. One wave (64 lanes) per destination node.
// Online softmax over CSR edge list; acc_v (128) + acc_a (64) in registers.
// Epilogue: out = acc_v + We * acc_a ; beta gate ; leaky relu ; write x_next.
// ---------------------------------------------------------------------------
#define ATT_WAVES 4
__global__ __launch_bounds__(256) void attn_kernel(
    const int* __restrict__ row_ptr, const int* __restrict__ esrc,
    const int* __restrict__ eidb,
    const float* __restrict__ Qb, const float* __restrict__ Kb,
    const float* __restrict__ Vb, const float* __restrict__ Sb,
    const float* __restrict__ QE, const float* __restrict__ Ae,
    const float* __restrict__ WeT,   // 64 x 128 = We^T
    const float* __restrict__ Wbeta, // 384
    float* __restrict__ Xout, int ldo, int Nn) {
    __shared__ float WeS[64 * 128];
    __shared__ float wbA[128], wbB[128];
    __shared__ float aaS[ATT_WAVES * 64];
    int t = threadIdx.x;
    for (int i = t; i < 64 * 128; i += 256) WeS[i] = WeT[i];
    if (t < 128) {
        float w3 = Wbeta[256 + t];
        wbA[t] = Wbeta[t] + w3;
        wbB[t] = Wbeta[128 + t] - w3;
    }
    __syncthreads();
    int wid = t >> 6, lane = t & 63;
    int wbase = wid * 64;
    const float RS = 0.088388347648318447f; // 1/sqrt(128)
    for (int n = blockIdx.x * ATT_WAVES + wid; n < Nn; n += gridDim.x * ATT_WAVES) {
        int r0 = row_ptr[n], r1 = row_ptr[n + 1];
        float q0  = Qb[(size_t)n * 128 + lane];
        float q1  = Qb[(size_t)n * 128 + 64 + lane];
        float qe0 = QE[(size_t)n * 64 + lane];
        float m = -INFINITY, l = 0.f;
        float av0 = 0.f, av1 = 0.f, aa = 0.f;
        for (int p = r0; p < r1; ++p) {
            int s = esrc[p];
            int e = eidb[p];
            const float* kr = &Kb[(size_t)s * 128];
            const float* vr = &Vb[(size_t)s * 128];
            const float* ar = &Ae[(size_t)e * 64];
            float k0 = kr[lane], k1 = kr[64 + lane];
            float v0 = vr[lane], v1 = vr[64 + lane];
            float a0 = ar[lane];
            float part = q0 * k0 + q1 * k1 + qe0 * a0;
#pragma unroll
            for (int off = 32; off; off >>= 1) part += __shfl_xor(part, off, 64);
            float sc = part * RS;
            float mn = fmaxf(m, sc);
            float scale = __expf(m - mn);   // m=-inf on first edge -> 0
            float w = __expf(sc - mn);
            l = l * scale + w;
            av0 = fmaf(w, v0, av0 * scale);
            av1 = fmaf(w, v1, av1 * scale);
            aa  = fmaf(w, a0, aa * scale);
            m = mn;
        }
        float inv = 1.0f / (l + 1e-16f);
        av0 *= inv; av1 *= inv; aa *= inv;
        aaS[wbase + lane] = aa;
        float out0 = av0, out1 = av1;
#pragma unroll
        for (int j = 0; j < 64; ++j) {
            float aj = aaS[wbase + j];
            out0 = fmaf(aj, WeS[j * 128 + lane], out0);
            out1 = fmaf(aj, WeS[j * 128 + 64 + lane], out1);
        }
        float xr0 = Sb[(size_t)n * 128 + lane];
        float xr1 = Sb[(size_t)n * 128 + 64 + lane];
        float bp = wbA[lane] * out0 + wbA[64 + lane] * out1 +
                   wbB[lane] * xr0  + wbB[64 + lane] * xr1;
#pragma unroll
        for (int off = 32; off; off >>= 1) bp += __shfl_xor(bp, off, 64);
        float beta = 1.0f / (1.0f + __expf(-bp));
        float x0 = beta * xr0 + (1.0f - beta) * out0;
        float x1 = beta * xr1 + (1.0f - beta) * out1;
        x0 = (x0 >= 0.f) ? x0 : 0.01f * x0;
        x1 = (x1 >= 0.f) ? x1 : 0.01f * x1;
        Xout[(size_t)n * ldo + lane]      = x0;
        Xout[(size_t)n * ldo + 64 + lane] = x1;
    }
}

// ---------------------------------------------------------------------------
extern "C" void kernel_launch(void* const* d_in, const int* in_sizes, int n_in,
                              void* d_out, int out_size, void* d_ws, size_t ws_size,
                              hipStream_t stream) {
    const float* x_in  = (const float*)d_in[0];
    const int*   eidx  = (const int*)d_in[1];
    const float* eatt  = (const float*)d_in[2];
    const float* Wq1 = (const float*)d_in[3];  const float* bq1 = (const float*)d_in[4];
    const float* Wk1 = (const float*)d_in[5];  const float* bk1 = (const float*)d_in[6];
    const float* Wv1 = (const float*)d_in[7];  const float* bv1 = (const float*)d_in[8];
    const float* We1 = (const float*)d_in[9];
    const float* Wskip1 = (const float*)d_in[10]; const float* bskip1 = (const float*)d_in[11];
    const float* Wbeta1 = (const float*)d_in[12];
    const float* Wq2 = (const float*)d_in[13]; const float* bq2 = (const float*)d_in[14];
    const float* Wk2 = (const float*)d_in[15]; const float* bk2 = (const float*)d_in[16];
    const float* Wv2 = (const float*)d_in[17]; const float* bv2 = (const float*)d_in[18];
    const float* We2 = (const float*)d_in[19];
    const float* Wskip2 = (const float*)d_in[20]; const float* bskip2 = (const float*)d_in[21];
    const float* Wbeta2 = (const float*)d_in[22];
    const float* Wm  = (const float*)d_in[23]; const float* bm  = (const float*)d_in[24];

    const int N = in_sizes[0] / 256;
    const int E = in_sizes[1] / 2;
    const int* srcp = eidx;
    const int* dstp = eidx + E;

    // ---- workspace carve (256B aligned) ----
    char* p = (char*)d_ws;
    auto alloc = [&](size_t bytes) -> void* {
        void* r = (void*)p;
        p += (bytes + 255) & ~(size_t)255;
        return r;
    };
    int* row_ptr  = (int*)alloc((size_t)(N + 1) * 4);
    int* fillb    = (int*)alloc((size_t)(N + 1) * 4);
    int* partials = (int*)alloc(256 * 4);
    int* esrc     = (int*)alloc((size_t)E * 4);
    int* eidb     = (int*)alloc((size_t)E * 4);
    float* Qb   = (float*)alloc((size_t)N * 128 * 4);
    float* Kb   = (float*)alloc((size_t)N * 128 * 4);
    float* Vb   = (float*)alloc((size_t)N * 128 * 4);
    float* Sb   = (float*)alloc((size_t)N * 128 * 4);
    float* QEb  = (float*)alloc((size_t)N * 64 * 4);
    float* xcat = (float*)alloc((size_t)N * 256 * 4);
    float* WeT  = (float*)alloc((size_t)64 * 128 * 4);

    // ---- CSR build ----
    hipMemsetAsync(fillb, 0, (size_t)(N + 1) * 4, stream);
    count_deg<<<(E + 255) / 256, 256, 0, stream>>>(dstp, fillb, E);
    int nScanBlocks = (N + 1 + 1023) / 1024;
    scan_a<<<nScanBlocks, 1024, 0, stream>>>(fillb, row_ptr, partials, N);
    scan_b<<<1, 1, 0, stream>>>(partials, nScanBlocks);
    scan_c<<<nScanBlocks, 1024, 0, stream>>>(row_ptr, partials, fillb, N);
    fill_edges<<<(E + 255) / 256, 256, 0, stream>>>(srcp, dstp, fillb, esrc, eidb, E);

    dim3 blk(256);
    int gx = (N + GBN - 1) / GBN;

    // ---- layer 1 ----
    transpose_we<<<(128 * 64 + 255) / 256, 256, 0, stream>>>(We1, WeT);
    gemm_nt<<<dim3(gx, 2), blk, 0, stream>>>(x_in, 256, Wq1, bq1, Qb, 128, N, 256);
    gemm_nt<<<dim3(gx, 2), blk, 0, stream>>>(x_in, 256, Wk1, bk1, Kb, 128, N, 256);
    gemm_nt<<<dim3(gx, 2), blk, 0, stream>>>(x_in, 256, Wv1, bv1, Vb, 128, N, 256);
    gemm_nt<<<dim3(gx, 2), blk, 0, stream>>>(x_in, 256, Wskip1, bskip1, Sb, 128, N, 256);
    gemm_nt<<<dim3(gx, 1), blk, 0, stream>>>(Qb, 128, WeT, nullptr, QEb, 64, N, 128);
    attn_kernel<<<1024, 256, 0, stream>>>(row_ptr, esrc, eidb, Qb, Kb, Vb, Sb, QEb,
                                          eatt, WeT, Wbeta1, xcat, 256, N);

    // ---- layer 2 (input = xcat[:, :128]) ----
    transpose_we<<<(128 * 64 + 255) / 256, 256, 0, stream>>>(We2, WeT);
    gemm_nt<<<dim3(gx, 2), blk, 0, stream>>>(xcat, 256, Wq2, bq2, Qb, 128, N, 128);
    gemm_nt<<<dim3(gx, 2), blk, 0, stream>>>(xcat, 256, Wk2, bk2, Kb, 128, N, 128);
    gemm_nt<<<dim3(gx, 2), blk, 0, stream>>>(xcat, 256, Wv2, bv2, Vb, 128, N, 128);
    gemm_nt<<<dim3(gx, 2), blk, 0, stream>>>(xcat, 256, Wskip2, bskip2, Sb, 128, N, 128);
    gemm_nt<<<dim3(gx, 1), blk, 0, stream>>>(Qb, 128, WeT, nullptr, QEb, 64, N, 128);
    attn_kernel<<<1024, 256, 0, stream>>>(row_ptr, esrc, eidb, Qb, Kb, Vb, Sb, QEb,
                                          eatt, WeT, Wbeta2, xcat + 128, 256, N);

    // ---- output MLP: d_out = xcat @ Wm^T + bm ----
    gemm_nt<<<dim3(gx, 1), blk, 0, stream>>>(xcat, 256, Wm, bm, (float*)d_out, 64, N, 256);
}

// Round 2
// 1279.488 us; speedup vs baseline: 1.3749x; 1.3749x over previous
//
#include <hip/hip_runtime.h>
#include <hip/hip_bf16.h>
#include <math.h>

// N=50000, E=800000, D_IN=256, D_E=64, H1=H2=128, N_OUT=64

#define GBN 64
#define GBO 64
#define GBK 16

// ---------------------------------------------------------------------------
// CSR build: degree count -> exclusive scan -> fill
// ---------------------------------------------------------------------------
__global__ void count_deg(const int* __restrict__ dst, int* __restrict__ cnt, int E) {
    int e = blockIdx.x * blockDim.x + threadIdx.x;
    if (e < E) atomicAdd(&cnt[dst[e]], 1);
}

__global__ __launch_bounds__(1024) void scan_a(const int* __restrict__ cnt,
                                               int* __restrict__ out,
                                               int* __restrict__ partials, int N) {
    __shared__ int sh[1024];
    int tid = threadIdx.x;
    int gid = blockIdx.x * 1024 + tid;
    int v = (gid < N) ? cnt[gid] : 0;
    sh[tid] = v;
    for (int off = 1; off < 1024; off <<= 1) {
        __syncthreads();
        int add = (tid >= off) ? sh[tid - off] : 0;
        __syncthreads();
        sh[tid] += add;
    }
    __syncthreads();
    if (gid <= N) out[gid] = sh[tid] - v;
    if (tid == 1023) partials[blockIdx.x] = sh[1023];
}

__global__ void scan_b(int* __restrict__ partials, int nb) {
    if (threadIdx.x == 0 && blockIdx.x == 0) {
        int run = 0;
        for (int i = 0; i < nb; ++i) { int t = partials[i]; partials[i] = run; run += t; }
    }
}

__global__ __launch_bounds__(1024) void scan_c(int* __restrict__ out,
                                               const int* __restrict__ partials,
                                               int* __restrict__ fillb, int N) {
    int gid = blockIdx.x * 1024 + threadIdx.x;
    if (gid <= N) {
        int v = out[gid] + partials[blockIdx.x];
        out[gid] = v;
        fillb[gid] = v;
    }
}

__global__ void fill_edges(const int* __restrict__ src, const int* __restrict__ dst,
                           int* __restrict__ fillb, int* __restrict__ esrc,
                           int* __restrict__ eidb, int E) {
    int e = blockIdx.x * blockDim.x + threadIdx.x;
    if (e < E) {
        int d = dst[e];
        int slot = atomicAdd(&fillb[d], 1);
        esrc[slot] = src[e];
        eidb[slot] = e;
    }
}

// ---------------------------------------------------------------------------
// We (128x64) -> WeT (64x128)
// ---------------------------------------------------------------------------
__global__ void transpose_we(const float* __restrict__ We, float* __restrict__ WeT) {
    int i = blockIdx.x * blockDim.x + threadIdx.x;
    if (i < 128 * 64) {
        int r = i >> 6, c = i & 63;
        WeT[c * 128 + r] = We[i];
    }
}

// ---------------------------------------------------------------------------
// NT GEMM: Out[n][o] = bias[o] + sum_k X[n][k] * W[o][k]
// ---------------------------------------------------------------------------
__global__ __launch_bounds__(256) void gemm_nt(const float* __restrict__ X, int ldx,
                                               const float* __restrict__ W,
                                               const float* __restrict__ bias,
                                               float* __restrict__ Out, int ldo,
                                               int Nrows, int K) {
    __shared__ float Xs[GBK][GBN];
    __shared__ float Ws[GBK][GBO];
    int n0 = blockIdx.x * GBN;
    int o0 = blockIdx.y * GBO;
    int t  = threadIdx.x;
    int tx = t & 15, ty = t >> 4;
    int lr = t >> 2;
    int lk = (t & 3) * 4;
    float acc[4][4] = {};
    for (int k0 = 0; k0 < K; k0 += GBK) {
        {
            int gr = n0 + lr;
            float4 xv = make_float4(0.f, 0.f, 0.f, 0.f);
            if (gr < Nrows)
                xv = *reinterpret_cast<const float4*>(&X[(size_t)gr * ldx + k0 + lk]);
            Xs[lk + 0][lr] = xv.x; Xs[lk + 1][lr] = xv.y;
            Xs[lk + 2][lr] = xv.z; Xs[lk + 3][lr] = xv.w;
            int go = o0 + lr;
            float4 wv = *reinterpret_cast<const float4*>(&W[(size_t)go * K + k0 + lk]);
            Ws[lk + 0][lr] = wv.x; Ws[lk + 1][lr] = wv.y;
            Ws[lk + 2][lr] = wv.z; Ws[lk + 3][lr] = wv.w;
        }
        __syncthreads();
#pragma unroll
        for (int k = 0; k < GBK; ++k) {
            float4 av = *reinterpret_cast<const float4*>(&Xs[k][ty * 4]);
            float4 bv = *reinterpret_cast<const float4*>(&Ws[k][tx * 4]);
            float a_[4] = {av.x, av.y, av.z, av.w};
            float b_[4] = {bv.x, bv.y, bv.z, bv.w};
#pragma unroll
            for (int i = 0; i < 4; ++i)
#pragma unroll
                for (int j = 0; j < 4; ++j)
                    acc[i][j] = fmaf(a_[i], b_[j], acc[i][j]);
        }
        __syncthreads();
    }
#pragma unroll
    for (int i = 0; i < 4; ++i) {
        int r = n0 + ty * 4 + i;
        if (r < Nrows) {
            int oc = o0 + tx * 4;
            float4 o4;
            o4.x = acc[i][0]; o4.y = acc[i][1]; o4.z = acc[i][2]; o4.w = acc[i][3];
            if (bias) {
                o4.x += bias[oc + 0]; o4.y += bias[oc + 1];
                o4.z += bias[oc + 2]; o4.w += bias[oc + 3];
            }
            *reinterpret_cast<float4*>(&Out[(size_t)r * ldo + oc]) = o4;
        }
    }
}

// ---------------------------------------------------------------------------
// Fused attention + epilogue, v2.
// One wave per destination node; 4-edge batches for MLP + shorter serial chains.
// QKVS layout: [N][512] = Q(0..127) | K(128..255) | V(256..383) | Skip(384..511)
// ---------------------------------------------------------------------------
#define AW 8
__global__ __launch_bounds__(512) void attn2(
    const int* __restrict__ row_ptr, const int* __restrict__ esrc,
    const int* __restrict__ eidb,
    const float* __restrict__ QKVS, const float* __restrict__ QE,
    const float* __restrict__ Ae,
    const float* __restrict__ WeT,   // 64 x 128
    const float* __restrict__ Wbeta, // 384
    float* __restrict__ Xout, int ldo, int Nn) {
    __shared__ float WeS[64 * 128];
    __shared__ float wbA[128], wbB[128];
    __shared__ float aaS[AW * 64];
    int t = threadIdx.x;
    for (int i = t; i < 64 * 128; i += 512) WeS[i] = WeT[i];
    if (t < 128) {
        float w3 = Wbeta[256 + t];
        wbA[t] = Wbeta[t] + w3;
        wbB[t] = Wbeta[128 + t] - w3;
    }
    __syncthreads();
    int wid = t >> 6, lane = t & 63;
    int wbase = wid << 6;
    const float RS = 0.088388347648318447f; // 1/sqrt(128)
    for (int n = blockIdx.x * AW + wid; n < Nn; n += gridDim.x * AW) {
        int r0 = row_ptr[n], r1 = row_ptr[n + 1];
        const float* qrow = QKVS + (size_t)n * 512;
        float q0  = qrow[lane];
        float q1  = qrow[64 + lane];
        float qe0 = QE[(size_t)n * 64 + lane];
        float m = -1e30f, l = 0.f;
        float av0 = 0.f, av1 = 0.f, aa = 0.f;
        for (int p = r0; p < r1; p += 4) {
            int pe = r1 - 1;
            int p1 = (p + 1 < r1) ? p + 1 : pe;
            int p2 = (p + 2 < r1) ? p + 2 : pe;
            int p3 = (p + 3 < r1) ? p + 3 : pe;
            int s0 = esrc[p],  s1 = esrc[p1], s2 = esrc[p2], s3 = esrc[p3];
            int e0 = eidb[p],  e1 = eidb[p1], e2 = eidb[p2], e3 = eidb[p3];
            const float* kr0 = QKVS + (size_t)s0 * 512 + 128;
            const float* kr1 = QKVS + (size_t)s1 * 512 + 128;
            const float* kr2 = QKVS + (size_t)s2 * 512 + 128;
            const float* kr3 = QKVS + (size_t)s3 * 512 + 128;
            // score operands first (k rows + a rows), then v rows (needed later)
            float k00 = kr0[lane], k01 = kr0[64 + lane];
            float k10 = kr1[lane], k11 = kr1[64 + lane];
            float k20 = kr2[lane], k21 = kr2[64 + lane];
            float k30 = kr3[lane], k31 = kr3[64 + lane];
            float a0 = Ae[(size_t)e0 * 64 + lane];
            float a1 = Ae[(size_t)e1 * 64 + lane];
            float a2 = Ae[(size_t)e2 * 64 + lane];
            float a3 = Ae[(size_t)e3 * 64 + lane];
            float v00 = kr0[128 + lane], v01 = kr0[192 + lane];
            float v10 = kr1[128 + lane], v11 = kr1[192 + lane];
            float v20 = kr2[128 + lane], v21 = kr2[192 + lane];
            float v30 = kr3[128 + lane], v31 = kr3[192 + lane];
            float d0 = fmaf(q0, k00, fmaf(q1, k01, qe0 * a0));
            float d1 = fmaf(q0, k10, fmaf(q1, k11, qe0 * a1));
            float d2 = fmaf(q0, k20, fmaf(q1, k21, qe0 * a2));
            float d3 = fmaf(q0, k30, fmaf(q1, k31, qe0 * a3));
#pragma unroll
            for (int off = 32; off; off >>= 1) {
                d0 += __shfl_xor(d0, off, 64);
                d1 += __shfl_xor(d1, off, 64);
                d2 += __shfl_xor(d2, off, 64);
                d3 += __shfl_xor(d3, off, 64);
            }
            float sc0 = d0 * RS;
            float sc1 = (p + 1 < r1) ? d1 * RS : -1e30f;
            float sc2 = (p + 2 < r1) ? d2 * RS : -1e30f;
            float sc3 = (p + 3 < r1) ? d3 * RS : -1e30f;
            float bm = fmaxf(fmaxf(sc0, sc1), fmaxf(sc2, sc3));
            float mn = fmaxf(m, bm);
            float scale = __expf(m - mn);
            float w0 = __expf(sc0 - mn);
            float w1 = __expf(sc1 - mn);
            float w2 = __expf(sc2 - mn);
            float w3 = __expf(sc3 - mn);
            l = fmaf(l, scale, (w0 + w1) + (w2 + w3));
            av0 = fmaf(av0, scale, fmaf(w0, v00, fmaf(w1, v10, fmaf(w2, v20, w3 * v30))));
            av1 = fmaf(av1, scale, fmaf(w0, v01, fmaf(w1, v11, fmaf(w2, v21, w3 * v31))));
            aa  = fmaf(aa,  scale, fmaf(w0, a0,  fmaf(w1, a1,  fmaf(w2, a2,  w3 * a3))));
            m = mn;
        }
        float inv = 1.0f / (l + 1e-16f);
        av0 *= inv; av1 *= inv; aa *= inv;
        aaS[wbase + lane] = aa;
        float out0 = av0, out1 = av1;
#pragma unroll
        for (int j = 0; j < 64; ++j) {
            float aj = aaS[wbase + j];
            out0 = fmaf(aj, WeS[j * 128 + lane], out0);
            out1 = fmaf(aj, WeS[j * 128 + 64 + lane], out1);
        }
        float xr0 = qrow[384 + lane];
        float xr1 = qrow[448 + lane];
        float bp = wbA[lane] * out0 + wbA[64 + lane] * out1 +
                   wbB[lane] * xr0  + wbB[64 + lane] * xr1;
#pragma unroll
        for (int off = 32; off; off >>= 1) bp += __shfl_xor(bp, off, 64);
        float beta = 1.0f / (1.0f + __expf(-bp));
        float x0 = beta * xr0 + (1.0f - beta) * out0;
        float x1 = beta * xr1 + (1.0f - beta) * out1;
        x0 = (x0 >= 0.f) ? x0 : 0.01f * x0;
        x1 = (x1 >= 0.f) ? x1 : 0.01f * x1;
        Xout[(size_t)n * ldo + lane]      = x0;
        Xout[(size_t)n * ldo + 64 + lane] = x1;
    }
}

// ---------------------------------------------------------------------------
extern "C" void kernel_launch(void* const* d_in, const int* in_sizes, int n_in,
                              void* d_out, int out_size, void* d_ws, size_t ws_size,
                              hipStream_t stream) {
    const float* x_in  = (const float*)d_in[0];
    const int*   eidx  = (const int*)d_in[1];
    const float* eatt  = (const float*)d_in[2];
    const float* Wq1 = (const float*)d_in[3];  const float* bq1 = (const float*)d_in[4];
    const float* Wk1 = (const float*)d_in[5];  const float* bk1 = (const float*)d_in[6];
    const float* Wv1 = (const float*)d_in[7];  const float* bv1 = (const float*)d_in[8];
    const float* We1 = (const float*)d_in[9];
    const float* Wskip1 = (const float*)d_in[10]; const float* bskip1 = (const float*)d_in[11];
    const float* Wbeta1 = (const float*)d_in[12];
    const float* Wq2 = (const float*)d_in[13]; const float* bq2 = (const float*)d_in[14];
    const float* Wk2 = (const float*)d_in[15]; const float* bk2 = (const float*)d_in[16];
    const float* Wv2 = (const float*)d_in[17]; const float* bv2 = (const float*)d_in[18];
    const float* We2 = (const float*)d_in[19];
    const float* Wskip2 = (const float*)d_in[20]; const float* bskip2 = (const float*)d_in[21];
    const float* Wbeta2 = (const float*)d_in[22];
    const float* Wm  = (const float*)d_in[23]; const float* bm  = (const float*)d_in[24];

    const int N = in_sizes[0] / 256;
    const int E = in_sizes[1] / 2;
    const int* srcp = eidx;
    const int* dstp = eidx + E;

    char* p = (char*)d_ws;
    auto alloc = [&](size_t bytes) -> void* {
        void* r = (void*)p;
        p += (bytes + 255) & ~(size_t)255;
        return r;
    };
    int* row_ptr  = (int*)alloc((size_t)(N + 1) * 4);
    int* fillb    = (int*)alloc((size_t)(N + 1) * 4);
    int* partials = (int*)alloc(256 * 4);
    int* esrc     = (int*)alloc((size_t)E * 4);
    int* eidb     = (int*)alloc((size_t)E * 4);
    float* QKVS = (float*)alloc((size_t)N * 512 * 4);   // Q|K|V|Skip fused rows
    float* QEb  = (float*)alloc((size_t)N * 64 * 4);
    float* xcat = (float*)alloc((size_t)N * 256 * 4);
    float* WeT  = (float*)alloc((size_t)64 * 128 * 4);

    // ---- CSR build ----
    hipMemsetAsync(fillb, 0, (size_t)(N + 1) * 4, stream);
    count_deg<<<(E + 255) / 256, 256, 0, stream>>>(dstp, fillb, E);
    int nScanBlocks = (N + 1 + 1023) / 1024;
    scan_a<<<nScanBlocks, 1024, 0, stream>>>(fillb, row_ptr, partials, N);
    scan_b<<<1, 1, 0, stream>>>(partials, nScanBlocks);
    scan_c<<<nScanBlocks, 1024, 0, stream>>>(row_ptr, partials, fillb, N);
    fill_edges<<<(E + 255) / 256, 256, 0, stream>>>(srcp, dstp, fillb, esrc, eidb, E);

    dim3 blk(256);
    int gx = (N + GBN - 1) / GBN;

    // ---- layer 1 ----
    transpose_we<<<(128 * 64 + 255) / 256, 256, 0, stream>>>(We1, WeT);
    gemm_nt<<<dim3(gx, 2), blk, 0, stream>>>(x_in, 256, Wq1, bq1, QKVS + 0,   512, N, 256);
    gemm_nt<<<dim3(gx, 2), blk, 0, stream>>>(x_in, 256, Wk1, bk1, QKVS + 128, 512, N, 256);
    gemm_nt<<<dim3(gx, 2), blk, 0, stream>>>(x_in, 256, Wv1, bv1, QKVS + 256, 512, N, 256);
    gemm_nt<<<dim3(gx, 2), blk, 0, stream>>>(x_in, 256, Wskip1, bskip1, QKVS + 384, 512, N, 256);
    gemm_nt<<<dim3(gx, 1), blk, 0, stream>>>(QKVS, 512, WeT, nullptr, QEb, 64, N, 128);
    attn2<<<1024, 512, 0, stream>>>(row_ptr, esrc, eidb, QKVS, QEb,
                                    eatt, WeT, Wbeta1, xcat, 256, N);

    // ---- layer 2 (input = xcat[:, :128]) ----
    transpose_we<<<(128 * 64 + 255) / 256, 256, 0, stream>>>(We2, WeT);
    gemm_nt<<<dim3(gx, 2), blk, 0, stream>>>(xcat, 256, Wq2, bq2, QKVS + 0,   512, N, 128);
    gemm_nt<<<dim3(gx, 2), blk, 0, stream>>>(xcat, 256, Wk2, bk2, QKVS + 128, 512, N, 128);
    gemm_nt<<<dim3(gx, 2), blk, 0, stream>>>(xcat, 256, Wv2, bv2, QKVS + 256, 512, N, 128);
    gemm_nt<<<dim3(gx, 2), blk, 0, stream>>>(xcat, 256, Wskip2, bskip2, QKVS + 384, 512, N, 128);
    gemm_nt<<<dim3(gx, 1), blk, 0, stream>>>(QKVS, 512, WeT, nullptr, QEb, 64, N, 128);
    attn2<<<1024, 512, 0, stream>>>(row_ptr, esrc, eidb, QKVS, QEb,
                                    eatt, WeT, Wbeta2, xcat + 128, 256, N);

    // ---- output MLP ----
    gemm_nt<<<dim3(gx, 1), blk, 0, stream>>>(xcat, 256, Wm, bm, (float*)d_out, 64, N, 256);
}

// Round 4
// 1145.109 us; speedup vs baseline: 1.5362x; 1.1173x over previous
//
#include <hip/hip_runtime.h>
#include <hip/hip_bf16.h>
#include <math.h>

// N=50000, E=800000, D_IN=256, D_E=64, H1=H2=128, N_OUT=64

// ---------------------------------------------------------------------------
// CSR build: degree count -> exclusive scan -> fill (int2 {src, edge_id})
// ---------------------------------------------------------------------------
__global__ void count_deg(const int* __restrict__ dst, int* __restrict__ cnt, int E) {
    int e = blockIdx.x * blockDim.x + threadIdx.x;
    if (e < E) atomicAdd(&cnt[dst[e]], 1);
}

__global__ __launch_bounds__(1024) void scan_a(const int* __restrict__ cnt,
                                               int* __restrict__ out,
                                               int* __restrict__ partials, int N) {
    __shared__ int sh[1024];
    int tid = threadIdx.x;
    int gid = blockIdx.x * 1024 + tid;
    int v = (gid < N) ? cnt[gid] : 0;
    sh[tid] = v;
    for (int off = 1; off < 1024; off <<= 1) {
        __syncthreads();
        int add = (tid >= off) ? sh[tid - off] : 0;
        __syncthreads();
        sh[tid] += add;
    }
    __syncthreads();
    if (gid <= N) out[gid] = sh[tid] - v;
    if (tid == 1023) partials[blockIdx.x] = sh[1023];
}

__global__ void scan_b(int* __restrict__ partials, int nb) {
    if (threadIdx.x == 0 && blockIdx.x == 0) {
        int run = 0;
        for (int i = 0; i < nb; ++i) { int t = partials[i]; partials[i] = run; run += t; }
    }
}

__global__ __launch_bounds__(1024) void scan_c(int* __restrict__ out,
                                               const int* __restrict__ partials,
                                               int* __restrict__ fillb, int N) {
    int gid = blockIdx.x * 1024 + threadIdx.x;
    if (gid <= N) {
        int v = out[gid] + partials[blockIdx.x];
        out[gid] = v;
        fillb[gid] = v;
    }
}

__global__ void fill_edges(const int* __restrict__ src, const int* __restrict__ dst,
                           int* __restrict__ fillb, int2* __restrict__ esi, int E) {
    int e = blockIdx.x * blockDim.x + threadIdx.x;
    if (e < E) {
        int d = dst[e];
        int slot = atomicAdd(&fillb[d], 1);
        esi[slot] = make_int2(src[e], e);
    }
}

// ---------------------------------------------------------------------------
// We (128x64) -> WeT (64x128)
// ---------------------------------------------------------------------------
__global__ void transpose_we(const float* __restrict__ We, float* __restrict__ WeT) {
    int i = blockIdx.x * blockDim.x + threadIdx.x;
    if (i < 128 * 64) {
        int r = i >> 6, c = i & 63;
        WeT[c * 128 + r] = We[i];
    }
}

// ---------------------------------------------------------------------------
// Wcat = [Wq; Wk; Wv; Wskip] (512 x K), bcat = [bq;bk;bv;bs]
// ---------------------------------------------------------------------------
__global__ void build_wcat(const float* __restrict__ Wq, const float* __restrict__ Wk,
                           const float* __restrict__ Wv, const float* __restrict__ Ws,
                           const float* __restrict__ bq, const float* __restrict__ bk,
                           const float* __restrict__ bv, const float* __restrict__ bs,
                           float* __restrict__ Wcat, float* __restrict__ bcat,
                           int K, int kshift) {
    int i = blockIdx.x * blockDim.x + threadIdx.x;
    int total = 512 * K;
    if (i < total) {
        int r = i >> kshift;
        float v;
        if (r < 128)      v = Wq[i];
        else if (r < 256) v = Wk[i - (128 << kshift)];
        else if (r < 384) v = Wv[i - (256 << kshift)];
        else              v = Ws[i - (384 << kshift)];
        Wcat[i] = v;
    }
    if (i < 128) {
        bcat[i]       = bq[i];
        bcat[128 + i] = bk[i];
        bcat[256 + i] = bv[i];
        bcat[384 + i] = bs[i];
    }
}

// ---------------------------------------------------------------------------
// NT GEMM v2: Out[n][o] = bias[o] + sum_k X[n][k]*W[o][k]
// 128x64 tile, 8x4 per thread, 256 threads, K-chunk 16
// ---------------------------------------------------------------------------
#define TM 128
#define TO 64
#define TKK 16
__global__ __launch_bounds__(256) void gemm_nt2(const float* __restrict__ X, int ldx,
                                                const float* __restrict__ W,
                                                const float* __restrict__ bias,
                                                float* __restrict__ Out, int ldo,
                                                int Nrows, int K) {
    __shared__ float Xs[TKK][TM];
    __shared__ float Ws[TKK][TO];
    int n0 = blockIdx.x * TM, o0 = blockIdx.y * TO;
    int t  = threadIdx.x;
    int tx = t & 15, ty = t >> 4;       // col grp (4 cols), row grp (8 rows)
    int lr = t >> 1, lk = (t & 1) * 8;  // X staging
    int wr = t >> 2, wk = (t & 3) * 4;  // W staging
    float acc[8][4] = {};
    for (int k0 = 0; k0 < K; k0 += TKK) {
        int gr = n0 + lr;
        float4 x0 = make_float4(0.f, 0.f, 0.f, 0.f);
        float4 x1 = make_float4(0.f, 0.f, 0.f, 0.f);
        if (gr < Nrows) {
            const float* xp = &X[(size_t)gr * ldx + k0 + lk];
            x0 = *reinterpret_cast<const float4*>(xp);
            x1 = *reinterpret_cast<const float4*>(xp + 4);
        }
        Xs[lk + 0][lr] = x0.x; Xs[lk + 1][lr] = x0.y;
        Xs[lk + 2][lr] = x0.z; Xs[lk + 3][lr] = x0.w;
        Xs[lk + 4][lr] = x1.x; Xs[lk + 5][lr] = x1.y;
        Xs[lk + 6][lr] = x1.z; Xs[lk + 7][lr] = x1.w;
        float4 wv = *reinterpret_cast<const float4*>(&W[(size_t)(o0 + wr) * K + k0 + wk]);
        Ws[wk + 0][wr] = wv.x; Ws[wk + 1][wr] = wv.y;
        Ws[wk + 2][wr] = wv.z; Ws[wk + 3][wr] = wv.w;
        __syncthreads();
#pragma unroll
        for (int k = 0; k < TKK; ++k) {
            float4 a0 = *reinterpret_cast<const float4*>(&Xs[k][ty * 8]);
            float4 a1 = *reinterpret_cast<const float4*>(&Xs[k][ty * 8 + 4]);
            float4 b  = *reinterpret_cast<const float4*>(&Ws[k][tx * 4]);
            float av_[8] = {a0.x, a0.y, a0.z, a0.w, a1.x, a1.y, a1.z, a1.w};
            float bv_[4] = {b.x, b.y, b.z, b.w};
#pragma unroll
            for (int i = 0; i < 8; ++i)
#pragma unroll
                for (int j = 0; j < 4; ++j)
                    acc[i][j] = fmaf(av_[i], bv_[j], acc[i][j]);
        }
        __syncthreads();
    }
#pragma unroll
    for (int i = 0; i < 8; ++i) {
        int r = n0 + ty * 8 + i;
        if (r < Nrows) {
            int oc = o0 + tx * 4;
            float4 o4;
            o4.x = acc[i][0]; o4.y = acc[i][1]; o4.z = acc[i][2]; o4.w = acc[i][3];
            if (bias) {
                o4.x += bias[oc + 0]; o4.y += bias[oc + 1];
                o4.z += bias[oc + 2]; o4.w += bias[oc + 3];
            }
            *reinterpret_cast<float4*>(&Out[(size_t)r * ldo + oc]) = o4;
        }
    }
}

// ---------------------------------------------------------------------------
// attn3: wave per node, 8-edge batches, no LDS, no epilogue.
// QKVS layout [N][512] = Q|K|V|Skip. Writes Acc[n][192] = av0|av1|aa (scaled).
// ---------------------------------------------------------------------------
#define AW3 4
__global__ __launch_bounds__(256) void attn3(
    const int* __restrict__ row_ptr, const int2* __restrict__ esi,
    const float* __restrict__ QKVS, const float* __restrict__ QE,
    const float* __restrict__ Ae, float* __restrict__ Acc, int Nn) {
    int t = threadIdx.x;
    int wid = t >> 6, lane = t & 63;
    const float RS = 0.088388347648318447f; // 1/sqrt(128)
    for (int n = blockIdx.x * AW3 + wid; n < Nn; n += gridDim.x * AW3) {
        int r0 = row_ptr[n], r1 = row_ptr[n + 1];
        const float* qrow = QKVS + (size_t)n * 512;
        float q0  = qrow[lane];
        float q1  = qrow[64 + lane];
        float qe0 = QE[(size_t)n * 64 + lane];
        float m = -1e30f, l = 0.f, av0 = 0.f, av1 = 0.f, aa = 0.f;
        for (int p = r0; p < r1; p += 8) {
            int pi[8];
#pragma unroll
            for (int i = 0; i < 8; ++i) pi[i] = (p + i < r1) ? p + i : r1 - 1;
            int2 se[8];
#pragma unroll
            for (int i = 0; i < 8; ++i) se[i] = esi[pi[i]];
            float k0v[8], k1v[8], a0v[8];
#pragma unroll
            for (int i = 0; i < 8; ++i) {
                const float* kr = QKVS + (size_t)se[i].x * 512 + 128;
                k0v[i] = kr[lane]; k1v[i] = kr[64 + lane];
            }
#pragma unroll
            for (int i = 0; i < 8; ++i) a0v[i] = Ae[(size_t)se[i].y * 64 + lane];
            float d[8];
#pragma unroll
            for (int i = 0; i < 8; ++i)
                d[i] = fmaf(q0, k0v[i], fmaf(q1, k1v[i], qe0 * a0v[i]));
#pragma unroll
            for (int off = 32; off; off >>= 1) {
#pragma unroll
                for (int i = 0; i < 8; ++i) d[i] += __shfl_xor(d[i], off, 64);
            }
            // V loads issued here; latency hidden under softmax math
            float v0v[8], v1v[8];
#pragma unroll
            for (int i = 0; i < 8; ++i) {
                const float* vr = QKVS + (size_t)se[i].x * 512 + 256;
                v0v[i] = vr[lane]; v1v[i] = vr[64 + lane];
            }
            float sc[8];
#pragma unroll
            for (int i = 0; i < 8; ++i) sc[i] = (p + i < r1) ? d[i] * RS : -1e30f;
            float bm = sc[0];
#pragma unroll
            for (int i = 1; i < 8; ++i) bm = fmaxf(bm, sc[i]);
            float mn = fmaxf(m, bm);
            float scale = __expf(m - mn);
            float w[8];
#pragma unroll
            for (int i = 0; i < 8; ++i) w[i] = __expf(sc[i] - mn);
            float ws = ((w[0] + w[1]) + (w[2] + w[3])) + ((w[4] + w[5]) + (w[6] + w[7]));
            l = fmaf(l, scale, ws);
            float s_aa = 0.f, s0 = 0.f, s1 = 0.f;
#pragma unroll
            for (int i = 0; i < 8; ++i) {
                s_aa = fmaf(w[i], a0v[i], s_aa);
                s0   = fmaf(w[i], v0v[i], s0);
                s1   = fmaf(w[i], v1v[i], s1);
            }
            aa  = fmaf(aa,  scale, s_aa);
            av0 = fmaf(av0, scale, s0);
            av1 = fmaf(av1, scale, s1);
            m = mn;
        }
        float inv = 1.0f / (l + 1e-16f);
        float* arow = Acc + (size_t)n * 192;
        arow[lane]       = av0 * inv;
        arow[64 + lane]  = av1 * inv;
        arow[128 + lane] = aa * inv;
    }
}

// ---------------------------------------------------------------------------
// epilogue: out = av + We*aa ; beta gate ; leaky relu ; write xcat half
// ---------------------------------------------------------------------------
__global__ __launch_bounds__(256) void epilogue_k(
    const float* __restrict__ Acc, const float* __restrict__ QKVS,
    const float* __restrict__ WeT, const float* __restrict__ Wbeta,
    float* __restrict__ Xout, int ldo, int Nn) {
    __shared__ float WeS[64 * 128];
    __shared__ float wbA[128], wbB[128];
    int t = threadIdx.x;
    for (int i = t; i < 64 * 128; i += 256) WeS[i] = WeT[i];
    if (t < 128) {
        float w3 = Wbeta[256 + t];
        wbA[t] = Wbeta[t] + w3;
        wbB[t] = Wbeta[128 + t] - w3;
    }
    __syncthreads();
    int wid = t >> 6, lane = t & 63;
    for (int n = blockIdx.x * 4 + wid; n < Nn; n += gridDim.x * 4) {
        const float* ar = Acc + (size_t)n * 192;
        float out0 = ar[lane], out1 = ar[64 + lane], aa = ar[128 + lane];
#pragma unroll
        for (int j = 0; j < 64; ++j) {
            float aj = __shfl(aa, j, 64);
            out0 = fmaf(aj, WeS[j * 128 + lane], out0);
            out1 = fmaf(aj, WeS[j * 128 + 64 + lane], out1);
        }
        const float* qrow = QKVS + (size_t)n * 512;
        float xr0 = qrow[384 + lane], xr1 = qrow[448 + lane];
        float bp = wbA[lane] * out0 + wbA[64 + lane] * out1 +
                   wbB[lane] * xr0  + wbB[64 + lane] * xr1;
#pragma unroll
        for (int off = 32; off; off >>= 1) bp += __shfl_xor(bp, off, 64);
        float beta = 1.0f / (1.0f + __expf(-bp));
        float x0 = beta * xr0 + (1.0f - beta) * out0;
        float x1 = beta * xr1 + (1.0f - beta) * out1;
        x0 = (x0 >= 0.f) ? x0 : 0.01f * x0;
        x1 = (x1 >= 0.f) ? x1 : 0.01f * x1;
        Xout[(size_t)n * ldo + lane]      = x0;
        Xout[(size_t)n * ldo + 64 + lane] = x1;
    }
}

// ---------------------------------------------------------------------------
extern "C" void kernel_launch(void* const* d_in, const int* in_sizes, int n_in,
                              void* d_out, int out_size, void* d_ws, size_t ws_size,
                              hipStream_t stream) {
    const float* x_in  = (const float*)d_in[0];
    const int*   eidx  = (const int*)d_in[1];
    const float* eatt  = (const float*)d_in[2];
    const float* Wq1 = (const float*)d_in[3];  const float* bq1 = (const float*)d_in[4];
    const float* Wk1 = (const float*)d_in[5];  const float* bk1 = (const float*)d_in[6];
    const float* Wv1 = (const float*)d_in[7];  const float* bv1 = (const float*)d_in[8];
    const float* We1 = (const float*)d_in[9];
    const float* Wskip1 = (const float*)d_in[10]; const float* bskip1 = (const float*)d_in[11];
    const float* Wbeta1 = (const float*)d_in[12];
    const float* Wq2 = (const float*)d_in[13]; const float* bq2 = (const float*)d_in[14];
    const float* Wk2 = (const float*)d_in[15]; const float* bk2 = (const float*)d_in[16];
    const float* Wv2 = (const float*)d_in[17]; const float* bv2 = (const float*)d_in[18];
    const float* We2 = (const float*)d_in[19];
    const float* Wskip2 = (const float*)d_in[20]; const float* bskip2 = (const float*)d_in[21];
    const float* Wbeta2 = (const float*)d_in[22];
    const float* Wm  = (const float*)d_in[23]; const float* bm  = (const float*)d_in[24];

    const int N = in_sizes[0] / 256;
    const int E = in_sizes[1] / 2;
    const int* srcp = eidx;
    const int* dstp = eidx + E;

    char* p = (char*)d_ws;
    auto alloc = [&](size_t bytes) -> void* {
        void* r = (void*)p;
        p += (bytes + 255) & ~(size_t)255;
        return r;
    };
    int*   row_ptr  = (int*)alloc((size_t)(N + 1) * 4);
    int*   fillb    = (int*)alloc((size_t)(N + 1) * 4);
    int*   partials = (int*)alloc(256 * 4);
    int2*  esi      = (int2*)alloc((size_t)E * 8);
    float* QKVS = (float*)alloc((size_t)N * 512 * 4);
    float* QEb  = (float*)alloc((size_t)N * 64 * 4);
    float* Accb = (float*)alloc((size_t)N * 192 * 4);
    float* xcat = (float*)alloc((size_t)N * 256 * 4);
    float* WeT  = (float*)alloc((size_t)64 * 128 * 4);
    float* Wcat = (float*)alloc((size_t)512 * 256 * 4);
    float* bcat = (float*)alloc((size_t)512 * 4);

    // ---- CSR build ----
    hipMemsetAsync(fillb, 0, (size_t)(N + 1) * 4, stream);
    count_deg<<<(E + 255) / 256, 256, 0, stream>>>(dstp, fillb, E);
    int nScanBlocks = (N + 1 + 1023) / 1024;
    scan_a<<<nScanBlocks, 1024, 0, stream>>>(fillb, row_ptr, partials, N);
    scan_b<<<1, 1, 0, stream>>>(partials, nScanBlocks);
    scan_c<<<nScanBlocks, 1024, 0, stream>>>(row_ptr, partials, fillb, N);
    fill_edges<<<(E + 255) / 256, 256, 0, stream>>>(srcp, dstp, fillb, esi, E);

    dim3 blk(256);
    int gx = (N + TM - 1) / TM;  // 391

    // ---- layer 1 ----
    build_wcat<<<(512 * 256 + 255) / 256, 256, 0, stream>>>(
        Wq1, Wk1, Wv1, Wskip1, bq1, bk1, bv1, bskip1, Wcat, bcat, 256, 8);
    transpose_we<<<(128 * 64 + 255) / 256, 256, 0, stream>>>(We1, WeT);
    gemm_nt2<<<dim3(gx, 8), blk, 0, stream>>>(x_in, 256, Wcat, bcat, QKVS, 512, N, 256);
    gemm_nt2<<<dim3(gx, 1), blk, 0, stream>>>(QKVS, 512, WeT, nullptr, QEb, 64, N, 128);
    attn3<<<2048, blk, 0, stream>>>(row_ptr, esi, QKVS, QEb, eatt, Accb, N);
    epilogue_k<<<1024, blk, 0, stream>>>(Accb, QKVS, WeT, Wbeta1, xcat, 256, N);

    // ---- layer 2 ----
    build_wcat<<<(512 * 128 + 255) / 256, 256, 0, stream>>>(
        Wq2, Wk2, Wv2, Wskip2, bq2, bk2, bv2, bskip2, Wcat, bcat, 128, 7);
    transpose_we<<<(128 * 64 + 255) / 256, 256, 0, stream>>>(We2, WeT);
    gemm_nt2<<<dim3(gx, 8), blk, 0, stream>>>(xcat, 256, Wcat, bcat, QKVS, 512, N, 128);
    gemm_nt2<<<dim3(gx, 1), blk, 0, stream>>>(QKVS, 512, WeT, nullptr, QEb, 64, N, 128);
    attn3<<<2048, blk, 0, stream>>>(row_ptr, esi, QKVS, QEb, eatt, Accb, N);
    epilogue_k<<<1024, blk, 0, stream>>>(Accb, QKVS, WeT, Wbeta2, xcat + 128, 256, N);

    // ---- output MLP ----
    gemm_nt2<<<dim3(gx, 1), blk, 0, stream>>>(xcat, 256, Wm, bm, (float*)d_out, 64, N, 256);
}